// Round 5
// baseline (146.974 us; speedup 1.0000x reference)
//
#include <hip/hip_runtime.h>
#include <hip/hip_bf16.h>

#define NUM_CLASSES 64
#define BATCH 16
#define CHAN 3
#define HW (512 * 512)
#define BPB 64          // blocks per batch image -> 1024 blocks
#define THREADS 256
#define WAVES 4
#define PXW 256         // pixels per wave per chunk (1KB per channel-slot)
#define CHUNK (PXW * WAVES)   // 1024 pixels per chunk per block
#define NCHUNK 4        // chunks per block: 4096 px/block
#define NREP 4          // histogram replicas
#define CPAD 8
#define SLOTS 7         // 3 in + 3 tgt + 1 mask

// gfx9 s_waitcnt encoding: [3:0]|[15:14]=vmcnt, [6:4]=expcnt, [11:8]=lgkmcnt
#define WAITCNT_VM7 0xF77   // vmcnt(7), lgkm/exp = no-wait
#define WAITCNT_VM0 0xF70   // vmcnt(0)

typedef __attribute__((address_space(3))) void* lds_vp;
typedef const __attribute__((address_space(1))) void* gm_vp;

// ---------------------------------------------------------------------------
// Kernel 1: per-(batch,class) sums/counts of channel-summed |in-tgt|.
// Global->LDS DMA staging (global_load_lds width=16): loads consume NO VGPRs,
// so each wave keeps 7KB (next chunk) in flight continuously, gated by manual
// s_waitcnt vmcnt(7).  Wave-private buffers -> no __syncthreads in the loop.
// ---------------------------------------------------------------------------
__global__ __launch_bounds__(THREADS) void frl_accum(
    const float* __restrict__ inp,    // [B,C,H,W]
    const float* __restrict__ tgt,
    const int*   __restrict__ mask,   // [B,H,W]
    float* __restrict__ g_sum,        // [B*64]
    unsigned int* __restrict__ g_cnt) // [B*64]
{
    __shared__ float lds[2][WAVES][SLOTS * PXW];      // 56 KB
    __shared__ float s_sum[NREP][NUM_CLASSES + CPAD];
    __shared__ unsigned int s_cnt[NREP][NUM_CLASSES + CPAD];

    const int t   = threadIdx.x;
    const int w   = t >> 6;           // wave id (uniform per wave)
    const int l   = t & 63;           // lane
    const int b   = blockIdx.x / BPB;
    const int blk = blockIdx.x % BPB;
    const int rep = t & (NREP - 1);

    const float* inb = inp  + (size_t)b * CHAN * HW;
    const float* tgb = tgt  + (size_t)b * CHAN * HW;
    const int*   mkb = mask + (size_t)b * HW;

    // stage chunk i into buffer buf: 7 x 1KB DMA per wave, no VGPR results
    auto stage = [&](int buf, int i) {
        const int px0 = blk * (CHUNK * NCHUNK) + i * CHUNK + w * PXW;
        float* ldsw = &lds[buf][w][0];
        #pragma unroll
        for (int c = 0; c < CHAN; ++c) {
            __builtin_amdgcn_global_load_lds(
                (gm_vp)(inb + c * HW + px0 + l * 4),
                (lds_vp)(ldsw + c * PXW), 16, 0, 0);
            __builtin_amdgcn_global_load_lds(
                (gm_vp)(tgb + c * HW + px0 + l * 4),
                (lds_vp)(ldsw + (3 + c) * PXW), 16, 0, 0);
        }
        __builtin_amdgcn_global_load_lds(
            (gm_vp)(mkb + px0 + l * 4),
            (lds_vp)(ldsw + 6 * PXW), 16, 0, 0);
    };

    // prologue: chunk 0 staging overlaps histogram init
    stage(0, 0);

    for (int i = t; i < NREP * (NUM_CLASSES + CPAD); i += THREADS) {
        ((float*)s_sum)[i] = 0.0f;
        ((unsigned int*)s_cnt)[i] = 0u;
    }
    __syncthreads();   // hist ready (also drains prologue staging — one-time)

    #pragma unroll
    for (int i = 0; i < NCHUNK; ++i) {
        const int buf = i & 1;
        if (i + 1 < NCHUNK) {
            stage(buf ^ 1, i + 1);                     // 7 more in flight
            __builtin_amdgcn_s_waitcnt(WAITCNT_VM7);   // wait chunk i only
        } else {
            __builtin_amdgcn_s_waitcnt(WAITCNT_VM0);
        }
        const float* ldsw = &lds[buf][w][0];
        const float4 a0 = *(const float4*)(ldsw + 0 * PXW + l * 4);
        const float4 a1 = *(const float4*)(ldsw + 1 * PXW + l * 4);
        const float4 a2 = *(const float4*)(ldsw + 2 * PXW + l * 4);
        const float4 b0 = *(const float4*)(ldsw + 3 * PXW + l * 4);
        const float4 b1 = *(const float4*)(ldsw + 4 * PXW + l * 4);
        const float4 b2 = *(const float4*)(ldsw + 5 * PXW + l * 4);
        const int4   m  = *(const int4*)  (ldsw + 6 * PXW + l * 4);

        const float l0 = fabsf(a0.x - b0.x) + fabsf(a1.x - b1.x) + fabsf(a2.x - b2.x);
        const float l1 = fabsf(a0.y - b0.y) + fabsf(a1.y - b1.y) + fabsf(a2.y - b2.y);
        const float l2 = fabsf(a0.z - b0.z) + fabsf(a1.z - b1.z) + fabsf(a2.z - b2.z);
        const float l3 = fabsf(a0.w - b0.w) + fabsf(a1.w - b1.w) + fabsf(a2.w - b2.w);

        atomicAdd(&s_sum[rep][m.x], l0);
        atomicAdd(&s_sum[rep][m.y], l1);
        atomicAdd(&s_sum[rep][m.z], l2);
        atomicAdd(&s_sum[rep][m.w], l3);
        atomicAdd(&s_cnt[rep][m.x], 1u);
        atomicAdd(&s_cnt[rep][m.y], 1u);
        atomicAdd(&s_cnt[rep][m.z], 1u);
        atomicAdd(&s_cnt[rep][m.w], 1u);
    }

    __syncthreads();
    if (t < NUM_CLASSES) {
        float fs = 0.0f;
        unsigned int cs = 0u;
        #pragma unroll
        for (int r = 0; r < NREP; ++r) { fs += s_sum[r][t]; cs += s_cnt[r][t]; }
        atomicAdd(&g_sum[b * NUM_CLASSES + t], fs);
        atomicAdd(&g_cnt[b * NUM_CLASSES + t], cs);
    }
}

// ---------------------------------------------------------------------------
// Kernel 2: avg = sum / max(3*cnt,1); max over avg; result =
//   ( Σ sums + Σ sums * clip(avg/max,0,1) ) / (B*C*H*W)     (BETA = 1)
// ---------------------------------------------------------------------------
__global__ __launch_bounds__(256) void frl_finalize(
    const float* __restrict__ g_sum,
    const unsigned int* __restrict__ g_cnt,
    float* __restrict__ out)
{
    const int NSEG = BATCH * NUM_CLASSES;     // 1024
    __shared__ float s_avg[BATCH * NUM_CLASSES];
    __shared__ float red[256];
    const int t = threadIdx.x;

    float lmax = 0.0f;
    for (int s = t; s < NSEG; s += 256) {
        const float sum = g_sum[s];
        const float cnt = (float)g_cnt[s];
        const float avg = sum / fmaxf(cnt * (float)CHAN, 1.0f);
        s_avg[s] = avg;
        lmax = fmaxf(lmax, avg);
    }
    red[t] = lmax;
    __syncthreads();
    for (int off = 128; off > 0; off >>= 1) {
        if (t < off) red[t] = fmaxf(red[t], red[t + off]);
        __syncthreads();
    }
    const float maxavg = fmaxf(red[0], 1e-30f);
    __syncthreads();

    float part = 0.0f;
    for (int s = t; s < NSEG; s += 256) {
        const float w = fminf(fmaxf(s_avg[s] / maxavg, 0.0f), 1.0f);
        part += g_sum[s] * (1.0f + w);
    }
    red[t] = part;
    __syncthreads();
    for (int off = 128; off > 0; off >>= 1) {
        if (t < off) red[t] += red[t + off];
        __syncthreads();
    }
    if (t == 0) {
        out[0] = red[0] / (float)((size_t)BATCH * CHAN * HW);
    }
}

extern "C" void kernel_launch(void* const* d_in, const int* in_sizes, int n_in,
                              void* d_out, int out_size, void* d_ws, size_t ws_size,
                              hipStream_t stream) {
    const float* inp = (const float*)d_in[0];
    const float* tgt = (const float*)d_in[1];
    const int* mask  = (const int*)d_in[2];

    float* g_sum        = (float*)d_ws;
    unsigned int* g_cnt = (unsigned int*)((char*)d_ws + BATCH * NUM_CLASSES * sizeof(float));

    hipMemsetAsync(d_ws, 0, 2 * BATCH * NUM_CLASSES * sizeof(float), stream);
    frl_accum<<<BATCH * BPB, THREADS, 0, stream>>>(inp, tgt, mask, g_sum, g_cnt);
    frl_finalize<<<1, 256, 0, stream>>>(g_sum, g_cnt, (float*)d_out);
}